// Round 2
// baseline (3302.485 us; speedup 1.0000x reference)
//
#include <hip/hip_runtime.h>
#include <cfloat>
#include <math.h>

#define D_DIM 1024
#define B_DIM 4
#define NQ    1024
#define NC    16384
#define TOPN  5
#define TOPA  8               // stage-A candidates per context split
#define CSPLIT 8              // context splits per batch
#define CAND  (TOPA*CSPLIT)   // 64 candidates per query
#define QT    64
#define CT    256
#define KT    32
#define DSTRIDE 260

// ---- lexicographic (value, index) top-N insert: replicates jax.lax.top_k stability ----
template<int N, typename T>
__device__ __forceinline__ void topk_insert(T (&bv)[N], int (&bi)[N], T v, int ci) {
    if (v < bv[N-1] || (v == bv[N-1] && ci < bi[N-1])) {
        bv[N-1] = v; bi[N-1] = ci;
        #pragma unroll
        for (int s = N-1; s > 0; --s) {
            bool sw = (bv[s] < bv[s-1]) || (bv[s] == bv[s-1] && bi[s] < bi[s-1]);
            if (sw) {
                T tv = bv[s-1]; bv[s-1] = bv[s]; bv[s] = tv;
                int ti = bi[s-1]; bi[s-1] = bi[s]; bi[s] = ti;
            }
        }
    }
}

// ---- Kernel 1: P64[m][e] = sum_d Q[m][d]*W[e][d] + b[e] in fp64 (exact ranking basis) ----
__global__ __launch_bounds__(256) void proj64_kernel(const float* __restrict__ Q,
                                                     const float* __restrict__ W,
                                                     const float* __restrict__ bias,
                                                     double* __restrict__ P64)
{
    __shared__ float Qs[KT][64];
    __shared__ float Ws[KT][64];
    const int m0 = blockIdx.y * 64;
    const int n0 = blockIdx.x * 64;
    const int t  = threadIdx.x;
    const int tm = t >> 4;
    const int tn = t & 15;
    double acc[4][4] = {};
    for (int k0 = 0; k0 < D_DIM; k0 += KT) {
        #pragma unroll
        for (int r = 0; r < 2; ++r) {
            int idx = t + r * 256;
            int row = idx >> 3;
            int kc  = idx & 7;
            float4 qa = *(const float4*)&Q[(size_t)(m0 + row) * D_DIM + k0 + kc * 4];
            float4 wa = *(const float4*)&W[(size_t)(n0 + row) * D_DIM + k0 + kc * 4];
            Qs[kc*4+0][row] = qa.x; Qs[kc*4+1][row] = qa.y; Qs[kc*4+2][row] = qa.z; Qs[kc*4+3][row] = qa.w;
            Ws[kc*4+0][row] = wa.x; Ws[kc*4+1][row] = wa.y; Ws[kc*4+2][row] = wa.z; Ws[kc*4+3][row] = wa.w;
        }
        __syncthreads();
        #pragma unroll
        for (int kk = 0; kk < KT; ++kk) {
            float4 a = *(const float4*)&Qs[kk][tm * 4];
            float4 w = *(const float4*)&Ws[kk][tn * 4];
            double av[4] = {a.x, a.y, a.z, a.w};
            double wv[4] = {w.x, w.y, w.z, w.w};
            #pragma unroll
            for (int i = 0; i < 4; ++i)
                #pragma unroll
                for (int j = 0; j < 4; ++j)
                    acc[i][j] = fma(av[i], wv[j], acc[i][j]);
        }
        __syncthreads();
    }
    #pragma unroll
    for (int i = 0; i < 4; ++i)
        #pragma unroll
        for (int j = 0; j < 4; ++j)
            P64[(size_t)(m0 + tm * 4 + i) * D_DIM + n0 + tn * 4 + j] =
                acc[i][j] + (double)bias[n0 + tn * 4 + j];
}

// ---- Kernel 2a: fp32 row squared norms of C (screening only) ----
__global__ __launch_bounds__(256) void rowsq_kernel(const float* __restrict__ X,
                                                    float* __restrict__ out, int nrows)
{
    int wave = threadIdx.x >> 6;
    int lane = threadIdx.x & 63;
    int row  = blockIdx.x * 4 + wave;
    if (row >= nrows) return;
    const float* x = X + (size_t)row * D_DIM;
    float s = 0.f;
    #pragma unroll
    for (int i = 0; i < 4; ++i) {
        float4 v = *(const float4*)&x[lane * 4 + i * 256];
        s += v.x * v.x + v.y * v.y + v.z * v.z + v.w * v.w;
    }
    #pragma unroll
    for (int off = 32; off; off >>= 1) s += __shfl_down(s, off, 64);
    if (lane == 0) out[row] = s;
}

// ---- Kernel 2b: fp32 row squared norms of P64 (screening only) ----
__global__ __launch_bounds__(256) void qsq_kernel(const double* __restrict__ P64,
                                                  float* __restrict__ out)
{
    int wave = threadIdx.x >> 6;
    int lane = threadIdx.x & 63;
    int row  = blockIdx.x * 4 + wave;
    const double* x = P64 + (size_t)row * D_DIM;
    float s = 0.f;
    #pragma unroll
    for (int i = 0; i < 8; ++i) {
        double2 v = *(const double2*)&x[lane * 2 + i * 128];
        float a = (float)v.x, b = (float)v.y;
        s += a * a + b * b;
    }
    #pragma unroll
    for (int off = 32; off; off >>= 1) s += __shfl_down(s, off, 64);
    if (lane == 0) out[row] = s;
}

// ---- Kernel 3: fp32 fused dist^2 + per-query top-8 candidates over a context split ----
// grid: (CSPLIT, NQ/QT, B), block 256. Each block: 64 queries x 2048 contexts.
__global__ __launch_bounds__(256) void dist_topk_kernel(const double* __restrict__ P64,
                                                        const float* __restrict__ C,
                                                        const float* __restrict__ qsq,
                                                        const float* __restrict__ csq,
                                                        int* __restrict__ pi)
{
    __shared__ float Qs[KT][QT];          // 8 KB
    __shared__ float CsBuf[KT * DSTRIDE]; // 33.3 KB; aliased as Dist[32][DSTRIDE] after GEMM
    const int t  = threadIdx.x;
    const int tq = t >> 5;                // 0..7
    const int tc = t & 31;                // 0..31
    const int csplit = blockIdx.x;
    const int by = blockIdx.y;
    const int bz = blockIdx.z;
    const int qg0 = bz * NQ + by * QT;

    float qs[8];
    #pragma unroll
    for (int i = 0; i < 8; ++i) qs[i] = qsq[qg0 + tq * 8 + i];

    float bv[TOPA]; int bi[TOPA];
    #pragma unroll
    for (int j = 0; j < TOPA; ++j) { bv[j] = FLT_MAX; bi[j] = 0x7fffffff; }

    const int cpb = NC / CSPLIT;          // 2048
    for (int ct = 0; ct < cpb / CT; ++ct) {
        const int cg0 = csplit * cpb + ct * CT;
        const size_t crow0 = (size_t)bz * NC + cg0;

        float acc[8][8] = {};
        for (int k0 = 0; k0 < D_DIM; k0 += KT) {
            // stage Qs from P64 (double -> float)
            #pragma unroll
            for (int r = 0; r < 2; ++r) {
                int idx = t + r * 256;
                int row = idx >> 3, kc = idx & 7;
                const double* src = &P64[(size_t)(qg0 + row) * D_DIM + k0 + kc * 4];
                double2 v0 = *(const double2*)src;
                double2 v1 = *(const double2*)(src + 2);
                Qs[kc*4+0][row] = (float)v0.x; Qs[kc*4+1][row] = (float)v0.y;
                Qs[kc*4+2][row] = (float)v1.x; Qs[kc*4+3][row] = (float)v1.y;
            }
            // stage Cs
            #pragma unroll
            for (int r = 0; r < 8; ++r) {
                int idx = t + r * 256;
                int crow = idx >> 3, kc = idx & 7;
                float4 v = *(const float4*)&C[(crow0 + crow) * D_DIM + k0 + kc * 4];
                CsBuf[(kc*4+0) * CT + crow] = v.x; CsBuf[(kc*4+1) * CT + crow] = v.y;
                CsBuf[(kc*4+2) * CT + crow] = v.z; CsBuf[(kc*4+3) * CT + crow] = v.w;
            }
            __syncthreads();
            #pragma unroll
            for (int kk = 0; kk < KT; ++kk) {
                const float4* qv = (const float4*)&Qs[kk][0];
                const float4* cv = (const float4*)&CsBuf[kk * CT];
                float4 a0 = qv[tq * 2], a1 = qv[tq * 2 + 1];
                float4 b0 = cv[tc * 2], b1 = cv[tc * 2 + 1];
                float av[8] = {a0.x, a0.y, a0.z, a0.w, a1.x, a1.y, a1.z, a1.w};
                float bb[8] = {b0.x, b0.y, b0.z, b0.w, b1.x, b1.y, b1.z, b1.w};
                #pragma unroll
                for (int i = 0; i < 8; ++i)
                    #pragma unroll
                    for (int j = 0; j < 8; ++j)
                        acc[i][j] = fmaf(av[i], bb[j], acc[i][j]);
            }
            __syncthreads();
        }

        float cs[8];
        {
            float4 c0 = *(const float4*)&csq[(size_t)bz * NC + cg0 + tc * 8];
            float4 c1 = *(const float4*)&csq[(size_t)bz * NC + cg0 + tc * 8 + 4];
            cs[0]=c0.x; cs[1]=c0.y; cs[2]=c0.z; cs[3]=c0.w;
            cs[4]=c1.x; cs[5]=c1.y; cs[6]=c1.z; cs[7]=c1.w;
        }
        float* Dist = CsBuf;
        #pragma unroll
        for (int h = 0; h < 2; ++h) {
            if ((tq >> 2) == h) {
                #pragma unroll
                for (int i = 0; i < 8; ++i) {
                    int r = (tq & 3) * 8 + i;
                    float4 w0, w1;
                    w0.x = fmaxf(qs[i] + cs[0] - 2.0f * acc[i][0], 0.0f);
                    w0.y = fmaxf(qs[i] + cs[1] - 2.0f * acc[i][1], 0.0f);
                    w0.z = fmaxf(qs[i] + cs[2] - 2.0f * acc[i][2], 0.0f);
                    w0.w = fmaxf(qs[i] + cs[3] - 2.0f * acc[i][3], 0.0f);
                    w1.x = fmaxf(qs[i] + cs[4] - 2.0f * acc[i][4], 0.0f);
                    w1.y = fmaxf(qs[i] + cs[5] - 2.0f * acc[i][5], 0.0f);
                    w1.z = fmaxf(qs[i] + cs[6] - 2.0f * acc[i][6], 0.0f);
                    w1.w = fmaxf(qs[i] + cs[7] - 2.0f * acc[i][7], 0.0f);
                    *(float4*)&Dist[r * DSTRIDE + tc * 8]     = w0;
                    *(float4*)&Dist[r * DSTRIDE + tc * 8 + 4] = w1;
                }
            }
            __syncthreads();
            if (tq == h) {
                const float* row = &Dist[tc * DSTRIDE];
                for (int i = 0; i < CT; ++i)
                    topk_insert<TOPA,float>(bv, bi, row[i], cg0 + i);
            }
            __syncthreads();
        }
    }

    if (t < 64) {
        size_t base = (((size_t)qg0 + t) * CSPLIT + csplit) * TOPA;
        #pragma unroll
        for (int j = 0; j < TOPA; ++j) pi[base + j] = bi[j];
    }
}

// ---- Kernel 4: fp64 exact refine of 64 candidates per query -> top-5, sqrt, outputs ----
__global__ __launch_bounds__(256) void refine_kernel(const double* __restrict__ P64,
                                                     const float* __restrict__ C,
                                                     const int*   __restrict__ pi,
                                                     float* __restrict__ out)
{
    __shared__ double dvs[CAND];
    __shared__ int    dis[CAND];
    const int q    = blockIdx.x;          // global query row 0..4095
    const int bz   = q >> 10;             // batch (NQ = 1024)
    const int t    = threadIdx.x;
    const int wave = t >> 6;
    const int lane = t & 63;
    const double* p = P64 + (size_t)q * D_DIM;

    for (int k = wave; k < CAND; k += 4) {
        int ci = pi[(size_t)q * CAND + k];
        const float* c = C + ((size_t)bz * NC + ci) * D_DIM;
        double s = 0.0;
        #pragma unroll
        for (int j = 0; j < 16; ++j) {
            int d = lane + 64 * j;
            double diff = p[d] - (double)c[d];
            s = fma(diff, diff, s);
        }
        #pragma unroll
        for (int off = 32; off; off >>= 1) s += __shfl_down(s, off, 64);
        if (lane == 0) { dvs[k] = s; dis[k] = ci; }
    }
    __syncthreads();
    if (t == 0) {
        double bv[TOPN]; int bi[TOPN];
        #pragma unroll
        for (int j = 0; j < TOPN; ++j) { bv[j] = DBL_MAX; bi[j] = 0x7fffffff; }
        for (int k = 0; k < CAND; ++k)
            topk_insert<TOPN,double>(bv, bi, dvs[k], dis[k]);
        #pragma unroll
        for (int j = 0; j < TOPN; ++j) {
            out[(size_t)q * TOPN + j] = (float)sqrt(bv[j]);
            out[(size_t)B_DIM * NQ * TOPN + (size_t)q * TOPN + j] = (float)bi[j];
        }
    }
}

extern "C" void kernel_launch(void* const* d_in, const int* in_sizes, int n_in,
                              void* d_out, int out_size, void* d_ws, size_t ws_size,
                              hipStream_t stream) {
    const float* Q    = (const float*)d_in[0];  // [4,1024,1024]
    const float* C    = (const float*)d_in[1];  // [4,16384,1024]
    const float* W    = (const float*)d_in[2];  // [1024,1024]
    const float* bias = (const float*)d_in[3];  // [1024]
    float* out = (float*)d_out;

    char* ws = (char*)d_ws;
    double* P64 = (double*)ws;                               // 4096*1024*8 = 32 MB
    float*  qsq = (float*)(ws + (size_t)4096 * 1024 * 8);    // 16 KB
    float*  csq = qsq + 4096;                                // 256 KB
    int*    pi  = (int*)(csq + 65536);                       // 4096*64*4 = 1 MB
    // total ~33.3 MB of workspace

    proj64_kernel<<<dim3(D_DIM / 64, (B_DIM * NQ) / 64), 256, 0, stream>>>(Q, W, bias, P64);
    qsq_kernel<<<(B_DIM * NQ) / 4, 256, 0, stream>>>(P64, qsq);
    rowsq_kernel<<<(B_DIM * NC) / 4, 256, 0, stream>>>(C, csq, B_DIM * NC);
    dist_topk_kernel<<<dim3(CSPLIT, NQ / QT, B_DIM), 256, 0, stream>>>(P64, C, qsq, csq, pi);
    refine_kernel<<<B_DIM * NQ, 256, 0, stream>>>(P64, C, pi, out);
}

// Round 3
// 1300.487 us; speedup vs baseline: 2.5394x; 2.5394x over previous
//
#include <hip/hip_runtime.h>
#include <cfloat>
#include <math.h>

#define D_DIM 1024
#define B_DIM 4
#define NQ    1024
#define NC    16384
#define TOPN  5
#define TOPA  8               // stage-A candidates per context split
#define CSPLIT 8              // context splits per batch
#define CAND  (TOPA*CSPLIT)   // 64 candidates per query
#define QT    64              // queries per block (dist kernel)
#define CTILE 128             // contexts per iteration (dist kernel)
#define BK    64              // K per LDS stage (bf16 elements)
#define LPAD  8
#define CSTR  (BK + LPAD)     // 72 shorts per LDS row (144B, 16B-aligned rows)

typedef __bf16 bf16x8 __attribute__((ext_vector_type(8)));
typedef float  f32x4  __attribute__((ext_vector_type(4)));
typedef short  short8 __attribute__((ext_vector_type(8)));

__device__ __forceinline__ unsigned short f2bf(float f) {
    unsigned u = __builtin_bit_cast(unsigned, f);
    unsigned r = (u + 0x7fffu + ((u >> 16) & 1u)) >> 16;
    return (unsigned short)r;
}

// ---- lexicographic (value, index) top-N insert (used by fp64 refine) ----
template<int N, typename T>
__device__ __forceinline__ void topk_insert(T (&bv)[N], int (&bi)[N], T v, int ci) {
    if (v < bv[N-1] || (v == bv[N-1] && ci < bi[N-1])) {
        bv[N-1] = v; bi[N-1] = ci;
        #pragma unroll
        for (int s = N-1; s > 0; --s) {
            bool sw = (bv[s] < bv[s-1]) || (bv[s] == bv[s-1] && bi[s] < bi[s-1]);
            if (sw) {
                T tv = bv[s-1]; bv[s-1] = bv[s]; bv[s] = tv;
                int ti = bi[s-1]; bi[s-1] = bi[s]; bi[s] = ti;
            }
        }
    }
}

// ---- value-only top-8 insert (screening; ties resolved by fp64 refine) ----
__device__ __forceinline__ void ins8(float (&bv)[TOPA], int (&bi)[TOPA], float v, int ci) {
    if (v < bv[TOPA-1]) {
        bv[TOPA-1] = v; bi[TOPA-1] = ci;
        #pragma unroll
        for (int s = TOPA-1; s > 0; --s) {
            if (bv[s] < bv[s-1]) {
                float tv = bv[s-1]; bv[s-1] = bv[s]; bv[s] = tv;
                int   ti = bi[s-1]; bi[s-1] = bi[s]; bi[s] = ti;
            }
        }
    }
}

// ---- Kernel 1: P64[m][e] = sum_d Q[m][d]*W[e][d] + b[e] in fp64 (exact ranking basis) ----
__global__ __launch_bounds__(256) void proj64_kernel(const float* __restrict__ Q,
                                                     const float* __restrict__ W,
                                                     const float* __restrict__ bias,
                                                     double* __restrict__ P64)
{
    __shared__ float Qs[32][64];
    __shared__ float Ws[32][64];
    const int m0 = blockIdx.y * 64;
    const int n0 = blockIdx.x * 64;
    const int t  = threadIdx.x;
    const int tm = t >> 4;
    const int tn = t & 15;
    double acc[4][4] = {};
    for (int k0 = 0; k0 < D_DIM; k0 += 32) {
        #pragma unroll
        for (int r = 0; r < 2; ++r) {
            int idx = t + r * 256;
            int row = idx >> 3;
            int kc  = idx & 7;
            float4 qa = *(const float4*)&Q[(size_t)(m0 + row) * D_DIM + k0 + kc * 4];
            float4 wa = *(const float4*)&W[(size_t)(n0 + row) * D_DIM + k0 + kc * 4];
            Qs[kc*4+0][row] = qa.x; Qs[kc*4+1][row] = qa.y; Qs[kc*4+2][row] = qa.z; Qs[kc*4+3][row] = qa.w;
            Ws[kc*4+0][row] = wa.x; Ws[kc*4+1][row] = wa.y; Ws[kc*4+2][row] = wa.z; Ws[kc*4+3][row] = wa.w;
        }
        __syncthreads();
        #pragma unroll
        for (int kk = 0; kk < 32; ++kk) {
            float4 a = *(const float4*)&Qs[kk][tm * 4];
            float4 w = *(const float4*)&Ws[kk][tn * 4];
            double av[4] = {a.x, a.y, a.z, a.w};
            double wv[4] = {w.x, w.y, w.z, w.w};
            #pragma unroll
            for (int i = 0; i < 4; ++i)
                #pragma unroll
                for (int j = 0; j < 4; ++j)
                    acc[i][j] = fma(av[i], wv[j], acc[i][j]);
        }
        __syncthreads();
    }
    #pragma unroll
    for (int i = 0; i < 4; ++i)
        #pragma unroll
        for (int j = 0; j < 4; ++j)
            P64[(size_t)(m0 + tm * 4 + i) * D_DIM + n0 + tn * 4 + j] =
                acc[i][j] + (double)bias[n0 + tn * 4 + j];
}

// ---- Kernel 2: csq (fp32 row squared norms of C) ----
__global__ __launch_bounds__(256) void rowsq_kernel(const float* __restrict__ X,
                                                    float* __restrict__ out, int nrows)
{
    int wave = threadIdx.x >> 6;
    int lane = threadIdx.x & 63;
    int row  = blockIdx.x * 4 + wave;
    if (row >= nrows) return;
    const float* x = X + (size_t)row * D_DIM;
    float s = 0.f;
    #pragma unroll
    for (int i = 0; i < 4; ++i) {
        float4 v = *(const float4*)&x[lane * 4 + i * 256];
        s += v.x * v.x + v.y * v.y + v.z * v.z + v.w * v.w;
    }
    #pragma unroll
    for (int off = 32; off; off >>= 1) s += __shfl_down(s, off, 64);
    if (lane == 0) out[row] = s;
}

// ---- Kernel 3: pack P64 -> bf16 Pbf + fp32 qsq ----
__global__ __launch_bounds__(256) void pack_q_kernel(const double* __restrict__ P64,
                                                     unsigned short* __restrict__ Pbf,
                                                     float* __restrict__ qsq)
{
    int wave = threadIdx.x >> 6;
    int lane = threadIdx.x & 63;
    int row  = blockIdx.x * 4 + wave;
    const double* x = P64 + (size_t)row * D_DIM;
    float s = 0.f;
    #pragma unroll
    for (int j = 0; j < 8; ++j) {
        double2 v = *(const double2*)&x[lane * 2 + j * 128];
        float a = (float)v.x, b = (float)v.y;
        s += a * a + b * b;
        ushort2 h; h.x = f2bf(a); h.y = f2bf(b);
        *(ushort2*)&Pbf[(size_t)row * D_DIM + lane * 2 + j * 128] = h;
    }
    #pragma unroll
    for (int off = 32; off; off >>= 1) s += __shfl_down(s, off, 64);
    if (lane == 0) qsq[row] = s;
}

// ---- Kernel 4: bf16-MFMA screening GEMM + per-lane register top-8 ----
// grid: (CSPLIT, NQ/QT, B), block 256 = 4 waves.
// Block tile: 64 queries x 128 contexts/iter x 2048 contexts/split.
// MFMA 16x16x32_bf16, A = contexts (m), B = queries (n).
// C/D layout: col(query) = lane&15, row(context) = (lane>>4)*4 + reg.
__global__ __launch_bounds__(256) void dist_mfma_kernel(const unsigned short* __restrict__ Pbf,
                                                        const float* __restrict__ C,
                                                        const float* __restrict__ qsq,
                                                        const float* __restrict__ csq,
                                                        int* __restrict__ pi)
{
    __shared__ __align__(16) char smem[32768];
    short* CsS = (short*)smem;                 // [CTILE][CSTR] = 18432 B
    short* QsS = (short*)(smem + CTILE * CSTR * 2); // [QT][CSTR] = 9216 B
    float* MV  = (float*)smem;                 // merge phase alias: [64][8][8]
    int*   MI  = (int*)(smem + 16384);

    const int t    = threadIdx.x;
    const int lane = t & 63;
    const int w    = t >> 6;
    const int wq   = w & 1;        // query half (32)
    const int wc   = w >> 1;       // context half (64)
    const int l15  = lane & 15;
    const int l4   = lane >> 4;    // 0..3
    const int csplit = blockIdx.x;
    const int by = blockIdx.y;
    const int bz = blockIdx.z;
    const int qg0 = bz * NQ + by * QT;

    // loop-invariant per-lane query norms (2 query columns)
    float qsv[2];
    #pragma unroll
    for (int s = 0; s < 2; ++s) qsv[s] = qsq[qg0 + wq * 32 + s * 16 + l15];

    float bv[2][TOPA]; int bi[2][TOPA];
    #pragma unroll
    for (int s = 0; s < 2; ++s)
        #pragma unroll
        for (int j = 0; j < TOPA; ++j) { bv[s][j] = FLT_MAX; bi[s][j] = 0x7fffffff; }

    const int cpb = NC / CSPLIT;   // 2048
    for (int it = 0; it < cpb / CTILE; ++it) {
        const int cg0 = csplit * cpb + it * CTILE;
        const size_t crow0 = (size_t)bz * NC + cg0;

        f32x4 acc[4][2];
        #pragma unroll
        for (int u = 0; u < 4; ++u)
            #pragma unroll
            for (int s = 0; s < 2; ++s) acc[u][s] = (f32x4)0.0f;

        for (int k0 = 0; k0 < D_DIM; k0 += BK) {
            __syncthreads();
            // stage C tile: 128 rows x 64 cols fp32 -> bf16 (4 chunks of 8 elems per thread)
            #pragma unroll
            for (int r = 0; r < 4; ++r) {
                int idx = t + r * 256;           // 0..1023
                int row = idx >> 3, ch = idx & 7;
                const float* src = &C[(crow0 + row) * (size_t)D_DIM + k0 + ch * 8];
                float4 f0 = *(const float4*)src;
                float4 f1 = *(const float4*)(src + 4);
                short8 h;
                h[0] = (short)f2bf(f0.x); h[1] = (short)f2bf(f0.y);
                h[2] = (short)f2bf(f0.z); h[3] = (short)f2bf(f0.w);
                h[4] = (short)f2bf(f1.x); h[5] = (short)f2bf(f1.y);
                h[6] = (short)f2bf(f1.z); h[7] = (short)f2bf(f1.w);
                *(short8*)&CsS[row * CSTR + ch * 8] = h;
            }
            // stage Q tile: 64 rows x 64 cols bf16 (2 chunks per thread)
            #pragma unroll
            for (int r = 0; r < 2; ++r) {
                int idx = t + r * 256;           // 0..511
                int row = idx >> 3, ch = idx & 7;
                short8 v = *(const short8*)&Pbf[(size_t)(qg0 + row) * D_DIM + k0 + ch * 8];
                *(short8*)&QsS[row * CSTR + ch * 8] = v;
            }
            __syncthreads();
            // 2 MFMA K-steps of 32
            #pragma unroll
            for (int ks = 0; ks < 2; ++ks) {
                const int kb = ks * 32 + l4 * 8;     // short offset in row
                bf16x8 bq[2], ac[4];
                #pragma unroll
                for (int s = 0; s < 2; ++s)
                    bq[s] = *(const bf16x8*)&QsS[(wq * 32 + s * 16 + l15) * CSTR + kb];
                #pragma unroll
                for (int u = 0; u < 4; ++u)
                    ac[u] = *(const bf16x8*)&CsS[(wc * 64 + u * 16 + l15) * CSTR + kb];
                #pragma unroll
                for (int u = 0; u < 4; ++u)
                    #pragma unroll
                    for (int s = 0; s < 2; ++s)
                        acc[u][s] = __builtin_amdgcn_mfma_f32_16x16x32_bf16(ac[u], bq[s], acc[u][s], 0, 0, 0);
            }
        }

        // d^2 = |q|^2 + |c|^2 - 2 q.c  -> per-lane register top-8 per query column
        #pragma unroll
        for (int u = 0; u < 4; ++u) {
            const int crow = wc * 64 + u * 16 + l4 * 4;   // context offset in tile
            float4 cs4 = *(const float4*)&csq[(size_t)bz * NC + cg0 + crow];
            float csa[4] = {cs4.x, cs4.y, cs4.z, cs4.w};
            #pragma unroll
            for (int s = 0; s < 2; ++s) {
                #pragma unroll
                for (int r = 0; r < 4; ++r) {
                    float v = qsv[s] + csa[r] - 2.0f * acc[u][s][r];
                    ins8(bv[s], bi[s], v, cg0 + crow + r);
                }
            }
        }
    }

    // merge 8 partial lists per query via LDS
    __syncthreads();
    #pragma unroll
    for (int s = 0; s < 2; ++s) {
        int qlocal = wq * 32 + s * 16 + l15;
        int lid = wc * 4 + l4;
        #pragma unroll
        for (int j = 0; j < TOPA; ++j) {
            MV[(qlocal * 8 + lid) * 8 + j] = bv[s][j];
            MI[(qlocal * 8 + lid) * 8 + j] = bi[s][j];
        }
    }
    __syncthreads();
    if (t < QT) {
        float mv[TOPA]; int mi[TOPA];
        #pragma unroll
        for (int j = 0; j < TOPA; ++j) { mv[j] = FLT_MAX; mi[j] = 0x7fffffff; }
        for (int l = 0; l < 8; ++l)
            #pragma unroll
            for (int j = 0; j < TOPA; ++j)
                ins8(mv, mi, MV[(t * 8 + l) * 8 + j], MI[(t * 8 + l) * 8 + j]);
        size_t base = (((size_t)qg0 + t) * CSPLIT + csplit) * TOPA;
        #pragma unroll
        for (int j = 0; j < TOPA; ++j) pi[base + j] = mi[j];
    }
}

// ---- Kernel 5: fp64 exact refine of 64 candidates per query -> top-5, sqrt, outputs ----
__global__ __launch_bounds__(256) void refine_kernel(const double* __restrict__ P64,
                                                     const float* __restrict__ C,
                                                     const int*   __restrict__ pi,
                                                     float* __restrict__ out)
{
    __shared__ double dvs[CAND];
    __shared__ int    dis[CAND];
    const int q    = blockIdx.x;
    const int bz   = q >> 10;
    const int t    = threadIdx.x;
    const int wave = t >> 6;
    const int lane = t & 63;
    const double* p = P64 + (size_t)q * D_DIM;

    for (int k = wave; k < CAND; k += 4) {
        int ci = pi[(size_t)q * CAND + k];
        const float* c = C + ((size_t)bz * NC + ci) * D_DIM;
        double s = 0.0;
        #pragma unroll
        for (int j = 0; j < 16; ++j) {
            int d = lane + 64 * j;
            double diff = p[d] - (double)c[d];
            s = fma(diff, diff, s);
        }
        #pragma unroll
        for (int off = 32; off; off >>= 1) s += __shfl_down(s, off, 64);
        if (lane == 0) { dvs[k] = s; dis[k] = ci; }
    }
    __syncthreads();
    if (t == 0) {
        double bv[TOPN]; int bi[TOPN];
        #pragma unroll
        for (int j = 0; j < TOPN; ++j) { bv[j] = DBL_MAX; bi[j] = 0x7fffffff; }
        for (int k = 0; k < CAND; ++k)
            topk_insert<TOPN,double>(bv, bi, dvs[k], dis[k]);
        #pragma unroll
        for (int j = 0; j < TOPN; ++j) {
            out[(size_t)q * TOPN + j] = (float)sqrt(bv[j]);
            out[(size_t)B_DIM * NQ * TOPN + (size_t)q * TOPN + j] = (float)bi[j];
        }
    }
}

extern "C" void kernel_launch(void* const* d_in, const int* in_sizes, int n_in,
                              void* d_out, int out_size, void* d_ws, size_t ws_size,
                              hipStream_t stream) {
    const float* Q    = (const float*)d_in[0];
    const float* C    = (const float*)d_in[1];
    const float* W    = (const float*)d_in[2];
    const float* bias = (const float*)d_in[3];
    float* out = (float*)d_out;

    char* ws = (char*)d_ws;
    double*         P64 = (double*)ws;                                  // 32 MB
    unsigned short* Pbf = (unsigned short*)(ws + (size_t)32 * 1024 * 1024);  // 8 MB
    float*          qsq = (float*)(ws + (size_t)40 * 1024 * 1024);      // 16 KB
    float*          csq = qsq + 4096;                                   // 256 KB
    int*            pi  = (int*)(csq + 65536);                          // 1 MB
    // total ~41.3 MB of workspace

    proj64_kernel<<<dim3(D_DIM / 64, (B_DIM * NQ) / 64), 256, 0, stream>>>(Q, W, bias, P64);
    pack_q_kernel<<<(B_DIM * NQ) / 4, 256, 0, stream>>>(P64, Pbf, qsq);
    rowsq_kernel<<<(B_DIM * NC) / 4, 256, 0, stream>>>(C, csq, B_DIM * NC);
    dist_mfma_kernel<<<dim3(CSPLIT, NQ / QT, B_DIM), 256, 0, stream>>>(Pbf, C, qsq, csq, pi);
    refine_kernel<<<B_DIM * NQ, 256, 0, stream>>>(P64, C, pi, out);
}